// Round 13
// baseline (161.110 us; speedup 1.0000x reference)
//
#include <hip/hip_runtime.h>

#define NF0 5
#define F1 320
#define F2 160
#define F3 80
#define NSUB 8          // XCD-local sub-bins (blockIdx & 7 proxy)
#define SUBCAP 512      // slots per (bin,sub); mean occupancy ~256

typedef float f32x4 __attribute__((ext_vector_type(4)));
typedef _Float16 f16x8 __attribute__((ext_vector_type(8)));

// ---------------- init: zero cursor region; detect ei width ----------------

__global__ void k_init(int* __restrict__ zreg, int zwords,
                       const unsigned int* __restrict__ ei32, int E, int* __restrict__ flag) {
    for (int t = blockIdx.x * 256 + threadIdx.x; t < zwords; t += gridDim.x * 256)
        zreg[t] = 0;
    if (blockIdx.x == 0) {
        __shared__ int ok;
        if (threadIdx.x == 0) ok = 1;
        __syncthreads();
        int np = E < 2048 ? E : 2048;
        for (int i = threadIdx.x; i < np; i += 256)
            if (ei32[2 * i + 1] != 0u) ok = 0;   // benign race
        __syncthreads();
        if (threadIdx.x == 0) *flag = ok;        // 1 => int64 storage, 0 => int32
    }
}

// ---------------- binA: bin edges by dst>>8, XCD-local sub-cursor/sub-region ----------------
// payload: {src | (dst&255)<<24, raw ew}. Requires src < 2^24 (N=100000 ok).

__global__ void k_binA(const void* ei, const float* __restrict__ ew, const int* __restrict__ flag,
                       int* __restrict__ bin_cnt /*stride 4 ints*/, int2* __restrict__ bins,
                       int n_bins, int* __restrict__ ovf_n, int* __restrict__ ovf,
                       int ovf_cap, int E) {
    int e = blockIdx.x * blockDim.x + threadIdx.x;
    if (e >= E) return;
    int sub = blockIdx.x & (NSUB - 1);
    int s, d;
    if (*flag) {
        const long long* p = (const long long*)ei;
        s = (int)p[e]; d = (int)p[E + e];
    } else {
        const int* p = (const int*)ei;
        s = p[e]; d = p[E + e];
    }
    float w = ew[e];
    int b = d >> 8;
    int pos = atomicAdd(&bin_cnt[(sub * n_bins + b) * 4], 1);
    if (pos < SUBCAP) {
        int2 pk;
        pk.x = s | ((d & 255) << 24);
        pk.y = __float_as_int(w);
        bins[(size_t)b * (NSUB * SUBCAP) + sub * SUBCAP + pos] = pk;
    } else {
        int o = atomicAdd(ovf_n, 1);
        if (o < ovf_cap) {
            ovf[3 * o] = s; ovf[3 * o + 1] = d; ovf[3 * o + 2] = __float_as_int(w);
        }
    }
}

// ---------------- binB1x: per-bin degree -> dinv;  + B-frags of f16(W2@We); + bc ----------------
// Blocks [0,n_bins): deg; [n_bins, n_bins+50): B-fragments; n_bins+50: bc.
// Fragment (kk, ct): lane l holds B[32*kk + 8*(l>>4) + i][16*ct + (l&15)], i=0..7.

__global__ __launch_bounds__(512) void k_binB1x(const int2* __restrict__ bins,
                                                const int* __restrict__ bin_cnt, int n_bins,
                                                float* __restrict__ dinv,
                                                const int* __restrict__ ovf_n,
                                                const int* __restrict__ ovf, int ovf_cap, int N,
                                                const float* __restrict__ W2,
                                                const float* __restrict__ We,
                                                _Float16* __restrict__ Bh,
                                                const float* __restrict__ b2,
                                                const float* __restrict__ be,
                                                float* __restrict__ bc) {
    __shared__ float deg_l[256];
    int b = blockIdx.x, t = threadIdx.x;
    if (b >= n_bins) {
        int xb = b - n_bins;
        if (xb < 50) {
            int idx = xb * 512 + t;          // 25600 B-frag elements
            int fid = idx >> 9;
            int rem = idx & 511;
            int lane = rem >> 3, i = rem & 7;
            int kk = fid / 5, ct = fid - kk * 5;
            int col = ct * 16 + (lane & 15);
            int row = kk * 32 + (lane >> 4) * 8 + i;
            const float* wr = W2 + (size_t)row * F2;
            float acc = 0.f;
            #pragma unroll 4
            for (int m = 0; m < F2; m += 4) {
                float4 w4 = *(const float4*)(wr + m);
                acc += w4.x * We[m * F3 + col] + w4.y * We[(m + 1) * F3 + col]
                     + w4.z * We[(m + 2) * F3 + col] + w4.w * We[(m + 3) * F3 + col];
            }
            Bh[((size_t)fid * 64 + lane) * 8 + i] = (_Float16)acc;   // RNE
        } else {
            if (t < F3) {
                float s = be[t];
                for (int k = 0; k < F2; ++k) s += b2[k] * We[k * F3 + t];
                bc[t] = s;
            }
        }
        return;
    }
    if (t < 256) deg_l[t] = 0.f;
    __syncthreads();
    int th = t >> 8;          // 0 or 1
    int tt = t & 255;
    for (int sp = 0; sp < NSUB; sp += 2) {
        int sub = sp + th;
        int ne = bin_cnt[(sub * n_bins + b) * 4]; if (ne > SUBCAP) ne = SUBCAP;
        const int2* bp = bins + (size_t)b * (NSUB * SUBCAP) + sub * SUBCAP;
        for (int j = tt; j < ne; j += 256) {
            int2 pk = bp[j];
            atomicAdd(&deg_l[((unsigned int)pk.x) >> 24], __int_as_float(pk.y));
        }
    }
    int n = *ovf_n; if (n > ovf_cap) n = ovf_cap;
    int lo = b * 256;
    for (int j = t; j < n; j += 512) {
        int d = ovf[3 * j + 1];
        if (d >= lo && d < lo + 256)
            atomicAdd(&deg_l[d - lo], __int_as_float(ovf[3 * j + 2]));
    }
    __syncthreads();
    int node = lo + t;
    if (t < 256 && node < N) dinv[node] = rsqrtf(1.0f + deg_l[t]);
}

// ---------------- FUSED binB2 + node transform ----------------
// Phase 1 (edge pass): bucket scatter {s, raw ew} + conv1 aggregate in LDS acc_l.
// Phase 2 (finalize): acc_l <- dinv[d]*acc + dinv[d]^2*x[d]  (= agg1, stays in LDS).
// Phase 3 (MFMA): t = relu(agg1@W1+b1) at fragment positions; g' = (t@Bf16)*dinv, f16.
// 512 thr = 8 waves x 2 sets x 16 nodes = 256 nodes/block. LDS 64.9 KB -> 2 blocks/CU.

__global__ __launch_bounds__(512) void k_binB2node(const int2* __restrict__ bins,
                                                   const int* __restrict__ bin_cnt, int n_bins,
                                                   const float* __restrict__ dinv,
                                                   const float* __restrict__ x,
                                                   const float* __restrict__ W1,
                                                   const float* __restrict__ b1,
                                                   const _Float16* __restrict__ Bh,
                                                   int* __restrict__ cnt,
                                                   int2* __restrict__ bucket, int cap,
                                                   int* __restrict__ ovf_n, int* __restrict__ ovf,
                                                   int ovf_cap,
                                                   _Float16* __restrict__ g, int N) {
    __shared__ int cnt_l[256];
    __shared__ float acc_l[256 * NF0];
    __shared__ float W_l[6 * F1];            // 7680 B: W1 rows then b1
    __shared__ _Float16 B_l[50 * 64 * 8];    // 51200 B: all 50 B-fragments
    int b = blockIdx.x, t = threadIdx.x;

    if (t < 480) {
        float4 v = (t < 400) ? ((const float4*)W1)[t] : ((const float4*)b1)[t - 400];
        ((float4*)W_l)[t] = v;
    }
    {
        const float4* src = (const float4*)Bh;
        float4* dst = (float4*)B_l;
        for (int i = t; i < 3200; i += 512) dst[i] = src[i];
    }
    if (t < 256) cnt_l[t] = 0;
    for (int q = t; q < 256 * NF0; q += 512) acc_l[q] = 0.f;
    int nsnap = *ovf_n; if (nsnap > ovf_cap) nsnap = ovf_cap;
    __syncthreads();
    int lo = b * 256;

    // binA-overflow conv1 contributions for this block's range (normally empty)
    for (int j = t; j < nsnap; j += 512) {
        int d = ovf[3 * j + 1];
        if (d >= lo && d < lo + 256) {
            int s = ovf[3 * j];
            float w = __int_as_float(ovf[3 * j + 2]) * dinv[s];
            const float* xs = x + (size_t)s * NF0;
            int dl = d - lo;
            #pragma unroll
            for (int f = 0; f < NF0; ++f)
                atomicAdd(&acc_l[dl * NF0 + f], xs[f] * w);
        }
    }

    // edge pass
    int th = t >> 8;
    int tt = t & 255;
    for (int sp = 0; sp < NSUB; sp += 2) {
        int sub = sp + th;
        int ne = bin_cnt[(sub * n_bins + b) * 4]; if (ne > SUBCAP) ne = SUBCAP;
        const int2* bp = bins + (size_t)b * (NSUB * SUBCAP) + sub * SUBCAP;
        for (int j = tt; j < ne; j += 256) {
            int2 pk = bp[j];
            int s = pk.x & 0xFFFFFF;
            int dl = ((unsigned int)pk.x) >> 24;
            int node = lo + dl;
            int pos = atomicAdd(&cnt_l[dl], 1);
            if (pos < cap) {
                int2 out_pk; out_pk.x = s; out_pk.y = pk.y;   // raw ew
                bucket[(size_t)node * cap + pos] = out_pk;
            } else {
                int o = atomicAdd(ovf_n, 1);
                if (o < ovf_cap) { ovf[3 * o] = s; ovf[3 * o + 1] = node; ovf[3 * o + 2] = pk.y; }
            }
            float w = __int_as_float(pk.y) * dinv[s];
            const float* xs = x + (size_t)s * NF0;
            float4 sv = *(const float4*)xs;   // 4B-aligned
            float s4 = xs[4];
            atomicAdd(&acc_l[dl * NF0 + 0], sv.x * w);
            atomicAdd(&acc_l[dl * NF0 + 1], sv.y * w);
            atomicAdd(&acc_l[dl * NF0 + 2], sv.z * w);
            atomicAdd(&acc_l[dl * NF0 + 3], sv.w * w);
            atomicAdd(&acc_l[dl * NF0 + 4], s4 * w);
        }
    }
    __syncthreads();

    // finalize agg1 in LDS; store cnt
    int node0 = lo + t;
    if (t < 256 && node0 < N) {
        float di = dinv[node0];
        float sc = di * di;
        const float* xn = x + (size_t)node0 * NF0;
        #pragma unroll
        for (int f = 0; f < NF0; ++f)
            acc_l[t * NF0 + f] = di * acc_l[t * NF0 + f] + sc * xn[f];
        int c = cnt_l[t]; if (c > cap) c = cap;
        cnt[node0] = c;
    }
    __syncthreads();

    // node transform: wave w -> sets {2w, 2w+1}, 16 nodes each
    int w = t >> 6, l = t & 63;
    int nl = l & 15, kg = l >> 4;
    f32x4 zero = {0.f, 0.f, 0.f, 0.f};
    const f16x8* blp = (const f16x8*)B_l;

    #pragma unroll
    for (int set = 0; set < 2; ++set) {
        int nlocal = w * 32 + set * 16 + nl;   // 0..255
        int base = lo + w * 32 + set * 16;
        float a0v[5];
        #pragma unroll
        for (int j = 0; j < 5; ++j) a0v[j] = acc_l[nlocal * NF0 + j];

        f32x4 acc[5] = {zero, zero, zero, zero, zero};
        #pragma unroll
        for (int kk = 0; kk < 10; ++kk) {
            int k0 = kk * 32 + kg * 8;
            float v0[8];
            const float* bb = W_l + 5 * F1 + k0;
            #pragma unroll
            for (int i = 0; i < 8; ++i) v0[i] = bb[i];
            #pragma unroll
            for (int j = 0; j < 5; ++j) {
                const float* wp = W_l + j * F1 + k0;
                float aj0 = a0v[j];
                #pragma unroll
                for (int i = 0; i < 8; ++i) v0[i] += aj0 * wp[i];
            }
            f16x8 ah0;
            #pragma unroll
            for (int i = 0; i < 8; ++i)
                ah0[i] = (_Float16)fmaxf(v0[i], 0.f);   // RNE
            #pragma unroll
            for (int ct = 0; ct < 5; ++ct) {
                f16x8 bf = blp[(kk * 5 + ct) * 64 + l];
                acc[ct] = __builtin_amdgcn_mfma_f32_16x16x32_f16(ah0, bf, acc[ct], 0, 0, 0);
            }
        }

        #pragma unroll
        for (int r = 0; r < 4; ++r) {
            int r0 = base + kg * 4 + r;
            if (r0 < N) {
                float dv = dinv[r0];
                #pragma unroll
                for (int ct = 0; ct < 5; ++ct)
                    g[(size_t)r0 * F3 + ct * 16 + nl] = (_Float16)(acc[ct][r] * dv);
            }
        }
    }
}

// ---------------- conv2 aggregation via bucket gather (f16 g', raw ew) -> d_out ----------------
// out[d] = dinv[d] * (sum_e ew*g'[s] + g'[d]) + bc.  10 threads/node, 8 cols (16 B) each.
// Non-temporal out stores (ext-vector f32x4): keep g' L2-resident.

__global__ __launch_bounds__(256) void k_aggB(const _Float16* __restrict__ g,
                                              const float* __restrict__ dinv,
                                              const float* __restrict__ bc,
                                              const int* __restrict__ cnt,
                                              const int2* __restrict__ bucket, int cap,
                                              float* __restrict__ out, int N) {
    int t = blockIdx.x * blockDim.x + threadIdx.x;
    if (t >= 10 * N) return;
    int i = t / 10;
    int c = (t - i * 10) << 3;   // col base: 0,8,...,72
    float acc[8];
    #pragma unroll
    for (int e = 0; e < 8; ++e) acc[e] = 0.f;
    int cn = cnt[i];
    const int4* row4 = (const int4*)(bucket + (size_t)i * cap);   // cap even -> 16B-aligned
    int j = 0;
    for (; j + 2 <= cn; j += 2) {
        int4 q = row4[j >> 1];
        float w0 = __int_as_float(q.y);
        float w1 = __int_as_float(q.w);
        f16x8 a0 = *(const f16x8*)(g + (size_t)q.x * F3 + c);
        f16x8 a1 = *(const f16x8*)(g + (size_t)q.z * F3 + c);
        #pragma unroll
        for (int e = 0; e < 8; ++e)
            acc[e] += (float)a0[e] * w0 + (float)a1[e] * w1;
    }
    if (j < cn) {
        int2 p0 = ((const int2*)row4)[j];
        float w0 = __int_as_float(p0.y);
        f16x8 a0 = *(const f16x8*)(g + (size_t)p0.x * F3 + c);
        #pragma unroll
        for (int e = 0; e < 8; ++e)
            acc[e] += (float)a0[e] * w0;
    }
    float di = dinv[i];
    f16x8 u0 = *(const f16x8*)(g + (size_t)i * F3 + c);
    const f32x4* bp = (const f32x4*)(bc + c);
    f32x4 q0 = bp[0], q1 = bp[1];
    f32x4 o0, o1;
    o0.x = di * (acc[0] + (float)u0[0]) + q0.x;
    o0.y = di * (acc[1] + (float)u0[1]) + q0.y;
    o0.z = di * (acc[2] + (float)u0[2]) + q0.z;
    o0.w = di * (acc[3] + (float)u0[3]) + q0.w;
    o1.x = di * (acc[4] + (float)u0[4]) + q1.x;
    o1.y = di * (acc[5] + (float)u0[5]) + q1.y;
    o1.z = di * (acc[6] + (float)u0[6]) + q1.z;
    o1.w = di * (acc[7] + (float)u0[7]) + q1.w;
    f32x4* op = (f32x4*)(out + (size_t)i * F3 + c);
    __builtin_nontemporal_store(o0, op);
    __builtin_nontemporal_store(o1, op + 1);
}

// all overflow edges (binA bin-full + binB2 bucket-full): out[d] += dinv[d]*ew*g'[s]
__global__ void k_fixB(const _Float16* __restrict__ g, const float* __restrict__ dinv,
                       const int* __restrict__ ovf_n, const int* __restrict__ ovf, int ovf_cap,
                       float* __restrict__ out) {
    int n = *ovf_n; if (n > ovf_cap) n = ovf_cap;
    for (int j = blockIdx.x * blockDim.x + threadIdx.x; j < n; j += gridDim.x * blockDim.x) {
        int s = ovf[3 * j], d = ovf[3 * j + 1];
        float w = dinv[d] * __int_as_float(ovf[3 * j + 2]);
        for (int f = 0; f < F3; ++f)
            atomicAdd(&out[(size_t)d * F3 + f], (float)g[(size_t)s * F3 + f] * w);
    }
}

// ---------------- launch ----------------

static inline size_t align256(size_t x) { return (x + 255) & ~(size_t)255; }

extern "C" void kernel_launch(void* const* d_in, const int* in_sizes, int n_in,
                              void* d_out, int out_size, void* d_ws, size_t ws_size,
                              hipStream_t stream) {
    const float* x  = (const float*)d_in[0];
    const void*  ei = d_in[1];
    const float* ew = (const float*)d_in[2];
    const float* W1 = (const float*)d_in[3];
    const float* b1 = (const float*)d_in[4];
    const float* W2 = (const float*)d_in[5];
    const float* b2 = (const float*)d_in[6];
    const float* We = (const float*)d_in[7];
    const float* be = (const float*)d_in[8];
    float* out = (float*)d_out;

    int N = in_sizes[0] / NF0;
    int E = in_sizes[2];

    const int OVF_CAP = 131072;              // safety net; ~never used
    int n_bins = (N + 255) >> 8;

    char* p = (char*)d_ws;
    auto alloc = [&](size_t bytes) { char* r = p; p += align256(bytes); return r; };
    int*   flag  = (int*)alloc(4);
    // zeroed-by-init region: ovf_n | pad | bin_cnt[NSUB*n_bins*4]
    int zwords = 16 + NSUB * n_bins * 4;
    int*   zreg  = (int*)alloc((size_t)zwords * 4);
    int*   ovf_n = zreg;
    int*   bin_cnt = zreg + 16;
    float* dinv  = (float*)alloc((size_t)N * 4);
    int*   cnt   = (int*)  alloc((size_t)N * 4);
    int*   ovf   = (int*)  alloc((size_t)OVF_CAP * 12);
    int2*  bins  = (int2*) alloc((size_t)n_bins * NSUB * SUBCAP * 8);
    float* bc    = (float*)alloc((size_t)F3 * 4);
    _Float16* Bh = (_Float16*)alloc((size_t)50 * 64 * 8 * 2);
    _Float16* g  = (_Float16*)alloc((size_t)N * F3 * 2);

    // adaptive bucket capacity (8 B/slot, EVEN for int4 loads); 24 => overflow ~0
    size_t used = (size_t)(p - (char*)d_ws);
    int cap = 24;
    if (ws_size > used) {
        size_t avail = (ws_size - used) / ((size_t)N * 8);
        if (avail < (size_t)cap) cap = (int)avail;
    } else cap = 4;
    cap &= ~1;
    if (cap < 4) cap = 4;
    int2* bucket = (int2*)alloc((size_t)N * cap * 8);

    int eb   = (E + 255) / 256;
    int zb   = (zwords + 255) / 256;

    k_init<<<zb, 256, 0, stream>>>(zreg, zwords, (const unsigned int*)ei, E, flag);
    k_binA<<<eb, 256, 0, stream>>>(ei, ew, flag, bin_cnt, bins, n_bins, ovf_n, ovf, OVF_CAP, E);
    k_binB1x<<<n_bins + 51, 512, 0, stream>>>(bins, bin_cnt, n_bins, dinv, ovf_n, ovf, OVF_CAP, N,
                                              W2, We, Bh, b2, be, bc);
    k_binB2node<<<n_bins, 512, 0, stream>>>(bins, bin_cnt, n_bins, dinv, x, W1, b1, Bh,
                                            cnt, bucket, cap, ovf_n, ovf, OVF_CAP, g, N);
    k_aggB<<<(10 * N + 255) / 256, 256, 0, stream>>>(g, dinv, bc, cnt, bucket, cap, out, N);
    k_fixB<<<16, 256, 0, stream>>>(g, dinv, ovf_n, ovf, OVF_CAP, out);
}

// Round 14
// 155.178 us; speedup vs baseline: 1.0382x; 1.0382x over previous
//
#include <hip/hip_runtime.h>

#define NF0 5
#define F1 320
#define F2 160
#define F3 80
#define NSUB 8          // XCD-local sub-bins (blockIdx & 7 proxy)
#define SUBCAP 512      // slots per (bin,sub); mean occupancy ~256

typedef float f32x4 __attribute__((ext_vector_type(4)));
typedef _Float16 f16x8 __attribute__((ext_vector_type(8)));

// ---------------- init: zero cursor region; detect ei width ----------------

__global__ void k_init(int* __restrict__ zreg, int zwords,
                       const unsigned int* __restrict__ ei32, int E, int* __restrict__ flag) {
    for (int t = blockIdx.x * 256 + threadIdx.x; t < zwords; t += gridDim.x * 256)
        zreg[t] = 0;
    if (blockIdx.x == 0) {
        __shared__ int ok;
        if (threadIdx.x == 0) ok = 1;
        __syncthreads();
        int np = E < 2048 ? E : 2048;
        for (int i = threadIdx.x; i < np; i += 256)
            if (ei32[2 * i + 1] != 0u) ok = 0;   // benign race
        __syncthreads();
        if (threadIdx.x == 0) *flag = ok;        // 1 => int64 storage, 0 => int32
    }
}

// ---------------- binA: bin edges by dst>>8, XCD-local sub-cursor/sub-region ----------------
// payload: {src | (dst&255)<<24, raw ew}. Requires src < 2^24 (N=100000 ok).

__global__ void k_binA(const void* ei, const float* __restrict__ ew, const int* __restrict__ flag,
                       int* __restrict__ bin_cnt /*stride 4 ints*/, int2* __restrict__ bins,
                       int n_bins, int* __restrict__ ovf_n, int* __restrict__ ovf,
                       int ovf_cap, int E) {
    int e = blockIdx.x * blockDim.x + threadIdx.x;
    if (e >= E) return;
    int sub = blockIdx.x & (NSUB - 1);
    int s, d;
    if (*flag) {
        const long long* p = (const long long*)ei;
        s = (int)p[e]; d = (int)p[E + e];
    } else {
        const int* p = (const int*)ei;
        s = p[e]; d = p[E + e];
    }
    float w = ew[e];
    int b = d >> 8;
    int pos = atomicAdd(&bin_cnt[(sub * n_bins + b) * 4], 1);
    if (pos < SUBCAP) {
        int2 pk;
        pk.x = s | ((d & 255) << 24);
        pk.y = __float_as_int(w);
        bins[(size_t)b * (NSUB * SUBCAP) + sub * SUBCAP + pos] = pk;
    } else {
        int o = atomicAdd(ovf_n, 1);
        if (o < ovf_cap) {
            ovf[3 * o] = s; ovf[3 * o + 1] = d; ovf[3 * o + 2] = __float_as_int(w);
        }
    }
}

// ---------------- binB1x: per-bin degree -> dinv;  + B-frags of f16(W2@We); + bc ----------------
// Blocks [0,n_bins): deg; [n_bins, n_bins+50): B-fragments; n_bins+50: bc.
// Fragment (kk, ct): lane l holds B[32*kk + 8*(l>>4) + i][16*ct + (l&15)], i=0..7.

__global__ __launch_bounds__(512) void k_binB1x(const int2* __restrict__ bins,
                                                const int* __restrict__ bin_cnt, int n_bins,
                                                float* __restrict__ dinv,
                                                const int* __restrict__ ovf_n,
                                                const int* __restrict__ ovf, int ovf_cap, int N,
                                                const float* __restrict__ W2,
                                                const float* __restrict__ We,
                                                _Float16* __restrict__ Bh,
                                                const float* __restrict__ b2,
                                                const float* __restrict__ be,
                                                float* __restrict__ bc) {
    __shared__ float deg_l[256];
    int b = blockIdx.x, t = threadIdx.x;
    if (b >= n_bins) {
        int xb = b - n_bins;
        if (xb < 50) {
            int idx = xb * 512 + t;          // 25600 B-frag elements
            int fid = idx >> 9;
            int rem = idx & 511;
            int lane = rem >> 3, i = rem & 7;
            int kk = fid / 5, ct = fid - kk * 5;
            int col = ct * 16 + (lane & 15);
            int row = kk * 32 + (lane >> 4) * 8 + i;
            const float* wr = W2 + (size_t)row * F2;
            float acc = 0.f;
            #pragma unroll 4
            for (int m = 0; m < F2; m += 4) {
                float4 w4 = *(const float4*)(wr + m);
                acc += w4.x * We[m * F3 + col] + w4.y * We[(m + 1) * F3 + col]
                     + w4.z * We[(m + 2) * F3 + col] + w4.w * We[(m + 3) * F3 + col];
            }
            Bh[((size_t)fid * 64 + lane) * 8 + i] = (_Float16)acc;   // RNE
        } else {
            if (t < F3) {
                float s = be[t];
                for (int k = 0; k < F2; ++k) s += b2[k] * We[k * F3 + t];
                bc[t] = s;
            }
        }
        return;
    }
    if (t < 256) deg_l[t] = 0.f;
    __syncthreads();
    int th = t >> 8;          // 0 or 1
    int tt = t & 255;
    for (int sp = 0; sp < NSUB; sp += 2) {
        int sub = sp + th;
        int ne = bin_cnt[(sub * n_bins + b) * 4]; if (ne > SUBCAP) ne = SUBCAP;
        const int2* bp = bins + (size_t)b * (NSUB * SUBCAP) + sub * SUBCAP;
        for (int j = tt; j < ne; j += 256) {
            int2 pk = bp[j];
            atomicAdd(&deg_l[((unsigned int)pk.x) >> 24], __int_as_float(pk.y));
        }
    }
    int n = *ovf_n; if (n > ovf_cap) n = ovf_cap;
    int lo = b * 256;
    for (int j = t; j < n; j += 512) {
        int d = ovf[3 * j + 1];
        if (d >= lo && d < lo + 256)
            atomicAdd(&deg_l[d - lo], __int_as_float(ovf[3 * j + 2]));
    }
    __syncthreads();
    int node = lo + t;
    if (t < 256 && node < N) dinv[node] = rsqrtf(1.0f + deg_l[t]);
}

// ---------------- binB2: bucket scatter {s, raw ew} + conv1 aggregate in LDS ----------------
// Small LDS (6 KB) -> high occupancy for the latency-bound gather phase.
// conv1: agg1[d] = dinv[d]*acc + dinv[d]^2*x[d], acc = sum_e ew*dinv[s]*x[s].

__global__ __launch_bounds__(512) void k_binB2(const int2* __restrict__ bins,
                                               const int* __restrict__ bin_cnt, int n_bins,
                                               const float* __restrict__ dinv,
                                               const float* __restrict__ x,
                                               int* __restrict__ cnt, int2* __restrict__ bucket,
                                               int cap, float* __restrict__ agg1,
                                               int* __restrict__ ovf_n, int* __restrict__ ovf,
                                               int ovf_cap, int N) {
    __shared__ int cnt_l[256];
    __shared__ float acc_l[256 * NF0];
    int b = blockIdx.x, t = threadIdx.x;
    if (t < 256) cnt_l[t] = 0;
    for (int q = t; q < 256 * NF0; q += 512) acc_l[q] = 0.f;
    int nsnap = *ovf_n; if (nsnap > ovf_cap) nsnap = ovf_cap;
    __syncthreads();
    int lo = b * 256;

    // binA-overflow conv1 contributions for this block's range (normally empty)
    for (int j = t; j < nsnap; j += 512) {
        int d = ovf[3 * j + 1];
        if (d >= lo && d < lo + 256) {
            int s = ovf[3 * j];
            float w = __int_as_float(ovf[3 * j + 2]) * dinv[s];
            const float* xs = x + (size_t)s * NF0;
            int dl = d - lo;
            #pragma unroll
            for (int f = 0; f < NF0; ++f)
                atomicAdd(&acc_l[dl * NF0 + f], xs[f] * w);
        }
    }

    int th = t >> 8;
    int tt = t & 255;
    for (int sp = 0; sp < NSUB; sp += 2) {
        int sub = sp + th;
        int ne = bin_cnt[(sub * n_bins + b) * 4]; if (ne > SUBCAP) ne = SUBCAP;
        const int2* bp = bins + (size_t)b * (NSUB * SUBCAP) + sub * SUBCAP;
        for (int j = tt; j < ne; j += 256) {
            int2 pk = bp[j];
            int s = pk.x & 0xFFFFFF;
            int dl = ((unsigned int)pk.x) >> 24;
            int node = lo + dl;
            int pos = atomicAdd(&cnt_l[dl], 1);
            if (pos < cap) {
                int2 out_pk; out_pk.x = s; out_pk.y = pk.y;   // raw ew
                bucket[(size_t)node * cap + pos] = out_pk;
            } else {
                int o = atomicAdd(ovf_n, 1);
                if (o < ovf_cap) { ovf[3 * o] = s; ovf[3 * o + 1] = node; ovf[3 * o + 2] = pk.y; }
            }
            float w = __int_as_float(pk.y) * dinv[s];
            const float* xs = x + (size_t)s * NF0;
            float4 sv = *(const float4*)xs;   // 4B-aligned
            float s4 = xs[4];
            atomicAdd(&acc_l[dl * NF0 + 0], sv.x * w);
            atomicAdd(&acc_l[dl * NF0 + 1], sv.y * w);
            atomicAdd(&acc_l[dl * NF0 + 2], sv.z * w);
            atomicAdd(&acc_l[dl * NF0 + 3], sv.w * w);
            atomicAdd(&acc_l[dl * NF0 + 4], s4 * w);
        }
    }
    __syncthreads();

    int node = lo + t;
    if (t < 256 && node < N) {
        float di = dinv[node];
        float sc = di * di;
        const float* xn = x + (size_t)node * NF0;
        float* op = agg1 + (size_t)node * NF0;
        #pragma unroll
        for (int f = 0; f < NF0; ++f)
            op[f] = di * acc_l[t * NF0 + f] + sc * xn[f];
        int c = cnt_l[t]; if (c > cap) c = cap;
        cnt[node] = c;
    }
}

// ---------------- node transform via MFMA (single f16 product); g' = g * dinv ----------------
// Block 512 = 8 waves; one set of 16 nodes per wave. W1+b1 AND B-fragments in LDS
// (58.9 KB -> 2 blocks/CU = 16 waves/CU). Inner loop: VALU + ds_read + MFMA, zero global.
// D: col=lane&15, row=(lane>>4)*4+reg. g' stored as f16 (RNE).

__global__ __launch_bounds__(512) void k_node(const float* __restrict__ agg1,
                                              const float* __restrict__ W1,
                                              const float* __restrict__ b1,
                                              const _Float16* __restrict__ Bh,
                                              const float* __restrict__ dinv,
                                              _Float16* __restrict__ g, int N) {
    __shared__ float W_l[6 * F1];            // 7680 B: W1 rows then b1
    __shared__ _Float16 B_l[50 * 64 * 8];    // 51200 B: all 50 fragments
    int tid = threadIdx.x;
    if (tid < 480) {
        float4 v = (tid < 400) ? ((const float4*)W1)[tid] : ((const float4*)b1)[tid - 400];
        ((float4*)W_l)[tid] = v;
    }
    {
        const float4* src = (const float4*)Bh;
        float4* dst = (float4*)B_l;
        for (int i = tid; i < 3200; i += 512) dst[i] = src[i];
    }
    __syncthreads();

    int w = tid >> 6, l = tid & 63;
    int nl = l & 15, kg = l >> 4;
    int base = blockIdx.x * 128 + w * 16;
    int n0 = base + nl;

    float a0v[5] = {0.f, 0.f, 0.f, 0.f, 0.f};
    if (n0 < N) {
        const float* ap = agg1 + (size_t)n0 * NF0;
        #pragma unroll
        for (int j = 0; j < 5; ++j) a0v[j] = ap[j];
    }

    f32x4 zero = {0.f, 0.f, 0.f, 0.f};
    f32x4 acc[5] = {zero, zero, zero, zero, zero};
    const f16x8* blp = (const f16x8*)B_l;

    #pragma unroll
    for (int kk = 0; kk < 10; ++kk) {
        int k0 = kk * 32 + kg * 8;
        float v0[8];
        const float* bb = W_l + 5 * F1 + k0;
        #pragma unroll
        for (int i = 0; i < 8; ++i) v0[i] = bb[i];
        #pragma unroll
        for (int j = 0; j < 5; ++j) {
            const float* wp = W_l + j * F1 + k0;
            float aj0 = a0v[j];
            #pragma unroll
            for (int i = 0; i < 8; ++i) v0[i] += aj0 * wp[i];
        }
        f16x8 ah0;
        #pragma unroll
        for (int i = 0; i < 8; ++i)
            ah0[i] = (_Float16)fmaxf(v0[i], 0.f);   // RNE
        #pragma unroll
        for (int ct = 0; ct < 5; ++ct) {
            f16x8 bf = blp[(kk * 5 + ct) * 64 + l];
            acc[ct] = __builtin_amdgcn_mfma_f32_16x16x32_f16(ah0, bf, acc[ct], 0, 0, 0);
        }
    }

    #pragma unroll
    for (int r = 0; r < 4; ++r) {
        int r0 = base + kg * 4 + r;
        if (r0 < N) {
            float dv = dinv[r0];
            #pragma unroll
            for (int ct = 0; ct < 5; ++ct)
                g[(size_t)r0 * F3 + ct * 16 + nl] = (_Float16)(acc[ct][r] * dv);
        }
    }
}

// ---------------- conv2 aggregation via bucket gather (f16 g', raw ew) -> d_out ----------------
// out[d] = dinv[d] * (sum_e ew*g'[s] + g'[d]) + bc.  10 threads/node, 8 cols (16 B) each.
// Overflow edges handled INLINE (ovf scan filtered by own node; free when ovf_n==0).
// Non-temporal out stores (ext-vector f32x4): keep g' L2-resident.

__global__ __launch_bounds__(256) void k_aggB(const _Float16* __restrict__ g,
                                              const float* __restrict__ dinv,
                                              const float* __restrict__ bc,
                                              const int* __restrict__ cnt,
                                              const int2* __restrict__ bucket, int cap,
                                              const int* __restrict__ ovf_n,
                                              const int* __restrict__ ovf, int ovf_cap,
                                              float* __restrict__ out, int N) {
    int t = blockIdx.x * blockDim.x + threadIdx.x;
    if (t >= 10 * N) return;
    int i = t / 10;
    int c = (t - i * 10) << 3;   // col base: 0,8,...,72
    float acc[8];
    #pragma unroll
    for (int e = 0; e < 8; ++e) acc[e] = 0.f;
    int cn = cnt[i];
    const int4* row4 = (const int4*)(bucket + (size_t)i * cap);   // cap even -> 16B-aligned
    int j = 0;
    for (; j + 2 <= cn; j += 2) {
        int4 q = row4[j >> 1];
        float w0 = __int_as_float(q.y);
        float w1 = __int_as_float(q.w);
        f16x8 a0 = *(const f16x8*)(g + (size_t)q.x * F3 + c);
        f16x8 a1 = *(const f16x8*)(g + (size_t)q.z * F3 + c);
        #pragma unroll
        for (int e = 0; e < 8; ++e)
            acc[e] += (float)a0[e] * w0 + (float)a1[e] * w1;
    }
    if (j < cn) {
        int2 p0 = ((const int2*)row4)[j];
        float w0 = __int_as_float(p0.y);
        f16x8 a0 = *(const f16x8*)(g + (size_t)p0.x * F3 + c);
        #pragma unroll
        for (int e = 0; e < 8; ++e)
            acc[e] += (float)a0[e] * w0;
    }
    // overflow edges targeting this node (normally ovf_n == 0)
    {
        int n = *ovf_n; if (n > ovf_cap) n = ovf_cap;
        for (int o = 0; o < n; ++o) {
            if (ovf[3 * o + 1] == i) {
                int s = ovf[3 * o];
                float w0 = __int_as_float(ovf[3 * o + 2]);
                f16x8 a0 = *(const f16x8*)(g + (size_t)s * F3 + c);
                #pragma unroll
                for (int e = 0; e < 8; ++e)
                    acc[e] += (float)a0[e] * w0;
            }
        }
    }
    float di = dinv[i];
    f16x8 u0 = *(const f16x8*)(g + (size_t)i * F3 + c);
    const f32x4* bp = (const f32x4*)(bc + c);
    f32x4 q0 = bp[0], q1 = bp[1];
    f32x4 o0, o1;
    o0.x = di * (acc[0] + (float)u0[0]) + q0.x;
    o0.y = di * (acc[1] + (float)u0[1]) + q0.y;
    o0.z = di * (acc[2] + (float)u0[2]) + q0.z;
    o0.w = di * (acc[3] + (float)u0[3]) + q0.w;
    o1.x = di * (acc[4] + (float)u0[4]) + q1.x;
    o1.y = di * (acc[5] + (float)u0[5]) + q1.y;
    o1.z = di * (acc[6] + (float)u0[6]) + q1.z;
    o1.w = di * (acc[7] + (float)u0[7]) + q1.w;
    f32x4* op = (f32x4*)(out + (size_t)i * F3 + c);
    __builtin_nontemporal_store(o0, op);
    __builtin_nontemporal_store(o1, op + 1);
}

// ---------------- launch ----------------

static inline size_t align256(size_t x) { return (x + 255) & ~(size_t)255; }

extern "C" void kernel_launch(void* const* d_in, const int* in_sizes, int n_in,
                              void* d_out, int out_size, void* d_ws, size_t ws_size,
                              hipStream_t stream) {
    const float* x  = (const float*)d_in[0];
    const void*  ei = d_in[1];
    const float* ew = (const float*)d_in[2];
    const float* W1 = (const float*)d_in[3];
    const float* b1 = (const float*)d_in[4];
    const float* W2 = (const float*)d_in[5];
    const float* b2 = (const float*)d_in[6];
    const float* We = (const float*)d_in[7];
    const float* be = (const float*)d_in[8];
    float* out = (float*)d_out;

    int N = in_sizes[0] / NF0;
    int E = in_sizes[2];

    const int OVF_CAP = 131072;              // safety net; ~never used
    int n_bins = (N + 255) >> 8;

    char* p = (char*)d_ws;
    auto alloc = [&](size_t bytes) { char* r = p; p += align256(bytes); return r; };
    int*   flag  = (int*)alloc(4);
    // zeroed-by-init region: ovf_n | pad | bin_cnt[NSUB*n_bins*4]
    int zwords = 16 + NSUB * n_bins * 4;
    int*   zreg  = (int*)alloc((size_t)zwords * 4);
    int*   ovf_n = zreg;
    int*   bin_cnt = zreg + 16;
    float* dinv  = (float*)alloc((size_t)N * 4);
    int*   cnt   = (int*)  alloc((size_t)N * 4);
    int*   ovf   = (int*)  alloc((size_t)OVF_CAP * 12);
    int2*  bins  = (int2*) alloc((size_t)n_bins * NSUB * SUBCAP * 8);
    float* agg1  = (float*)alloc((size_t)N * NF0 * 4);
    float* bc    = (float*)alloc((size_t)F3 * 4);
    _Float16* Bh = (_Float16*)alloc((size_t)50 * 64 * 8 * 2);
    _Float16* g  = (_Float16*)alloc((size_t)N * F3 * 2);

    // adaptive bucket capacity (8 B/slot, EVEN for int4 loads); 24 => overflow ~0
    size_t used = (size_t)(p - (char*)d_ws);
    int cap = 24;
    if (ws_size > used) {
        size_t avail = (ws_size - used) / ((size_t)N * 8);
        if (avail < (size_t)cap) cap = (int)avail;
    } else cap = 4;
    cap &= ~1;
    if (cap < 4) cap = 4;
    int2* bucket = (int2*)alloc((size_t)N * cap * 8);

    int eb   = (E + 255) / 256;
    int zb   = (zwords + 255) / 256;

    k_init<<<zb, 256, 0, stream>>>(zreg, zwords, (const unsigned int*)ei, E, flag);
    k_binA<<<eb, 256, 0, stream>>>(ei, ew, flag, bin_cnt, bins, n_bins, ovf_n, ovf, OVF_CAP, E);
    k_binB1x<<<n_bins + 51, 512, 0, stream>>>(bins, bin_cnt, n_bins, dinv, ovf_n, ovf, OVF_CAP, N,
                                              W2, We, Bh, b2, be, bc);
    k_binB2<<<n_bins, 512, 0, stream>>>(bins, bin_cnt, n_bins, dinv, x, cnt, bucket, cap,
                                        agg1, ovf_n, ovf, OVF_CAP, N);
    k_node<<<(N + 127) / 128, 512, 0, stream>>>(agg1, W1, b1, Bh, dinv, g, N);
    k_aggB<<<(10 * N + 255) / 256, 256, 0, stream>>>(g, dinv, bc, cnt, bucket, cap,
                                                     ovf_n, ovf, OVF_CAP, out, N);
}